// Round 5
// baseline (704.913 us; speedup 1.0000x reference)
//
#include <hip/hip_runtime.h>

typedef _Float16 f16;
typedef _Float16 f16x8 __attribute__((ext_vector_type(8)));
typedef _Float16 f16x4 __attribute__((ext_vector_type(4)));
typedef float    f32x16 __attribute__((ext_vector_type(16)));

#define GLD16(g, l)                                                            \
  __builtin_amdgcn_global_load_lds(                                            \
      (const __attribute__((address_space(1))) void*)(g),                      \
      (__attribute__((address_space(3))) void*)(l), 16, 0, 0)

static constexpr int S = 4096, H = 2048, B = 2;

// ------------------------------------------- single fused cast: hs | Wq|Wk|Wv
__global__ __launch_bounds__(256) void cast_all(
    const float* __restrict__ hs, const float* __restrict__ w0,
    const float* __restrict__ w1, const float* __restrict__ w2,
    f16* __restrict__ hs_h, f16* __restrict__ w_h) {
  const int hsN4 = B * S * H / 4;  // float4 groups in hs
  const int wN4  = H * H / 4;     // float4 groups per weight
  int i = blockIdx.x * 256 + threadIdx.x;
  float4 f;
  if (i < hsN4) {
    f = reinterpret_cast<const float4*>(hs)[i];
    f16x4 h = {(f16)f.x, (f16)f.y, (f16)f.z, (f16)f.w};
    reinterpret_cast<f16x4*>(hs_h)[i] = h;
  } else {
    int j = i - hsN4;
    int seg = j / wN4, off = j - seg * wN4;
    const float* src = seg == 0 ? w0 : (seg == 1 ? w1 : w2);
    f = reinterpret_cast<const float4*>(src)[off];
    f16x4 h = {(f16)f.x, (f16)f.y, (f16)f.z, (f16)f.w};
    reinterpret_cast<f16x4*>(w_h)[j] = h;
  }
}

// ---------------------------------------------------------------- TN GEMM
// C[m,n] = sum_k A[m,k]*B[n,k].
// BM=256 x BN=256 tile, BK=64, 512 threads = 8 waves (2M x 4N), per-wave
// 128x64 output as 4x2 of 32x32x16 MFMA (acc = 128 regs).
// DBUF=false: SINGLE 64KB LDS buffer -> TWO blocks co-resident per CU
//   (4 waves/SIMD). Per tile: {8 GLD; vmcnt0; bar; compute; bar}. The stage
//   wait + lgkm stalls of one block are covered by the other block's MFMAs
//   (m114 cross-block overlap) -- the thing no intra-block schedule at
//   2 waves/SIMD could provide (r1-r4 all null at 35-41% MfmaUtil).
// DBUF=true: r4's 128KB double-buffer + prefetch (for PV whose 256-block
//   grid is 1 block/CU -- single-buffer would expose stage latency there).
// Compute: register-pipelined chunks (issue chunk c+1 ds_reads before chunk
// c's MFMAs; compiler emits counted lgkmcnt).
// LDS swizzle (proven): chunk (row,kc) stored at line-slot
// kc ^ (row&7) ^ ((row&16)>>2); read uses same XOR involution.
// MODE 0: fused QKV.  n<2048 -> Q(+bq) f16; <4096 -> K(+bk); else Vt[b][h][s](+bv)
// MODE 2: scores, batched. f16 out = v*scale + mask[b][n]
// MODE 3: PV, batched. f32 out.
template <int MODE, bool DBUF>
__global__ __launch_bounds__(512, 2) void gemm_tn(
    const f16* __restrict__ A, const f16* __restrict__ Bm,
    void* __restrict__ C0, void* __restrict__ C1, void* __restrict__ C2,
    const float* __restrict__ x0, const float* __restrict__ x1,
    const float* __restrict__ x2, float scale, int K, int lda, int ldb) {
  __shared__ __attribute__((aligned(16))) char smem[DBUF ? 131072 : 65536];

  const int tileM = blockIdx.y * 256;
  const int tileN = blockIdx.x * 256;

  const int tid  = threadIdx.x;
  const int wave = tid >> 6, lane = tid & 63;
  const int wm = (wave >> 2) * 128;  // 0,128
  const int wn = (wave & 3) * 64;    // 0,64,128,192
  const int l31 = lane & 31, khalf = lane >> 5;

  f32x16 acc[4][2] = {};

  // batch-aware operand row bases (tiles never straddle batches: S%256==0)
  size_t rowB = tileN;
  if (MODE == 2) rowB = (size_t)(tileM >> 12) * S + tileN;  // Kh row = b*S + k
  if (MODE == 3) rowB = (size_t)(tileM >> 12) * H + tileN;  // Vt row = b*H + h
  const f16* gA = A + (size_t)tileM * lda;
  const f16* gB = Bm + rowB * ldb;

  // staging offsets: 256 rows x 8 chunks(16B) per operand = 4 gloads each
  int aoff[4], boff[4], loff[4];
#pragma unroll
  for (int j = 0; j < 4; ++j) {
    int id = j * 512 + tid;
    int r = id >> 3, cs = (id & 7) ^ (r & 7) ^ ((r & 16) >> 2);
    aoff[j] = r * lda + cs * 8;
    boff[j] = r * ldb + cs * 8;
    loff[j] = id * 8;
  }

  // fragment-read swizzle term (row&7 == l31&7, row&16 == l31&16 for all frags)
  const int rsw = (l31 & 7) ^ ((l31 & 16) >> 2);
  const int nt = K >> 6;

  // fragment row addresses (f16 index), reused every tile
  int arow[4], brow[2];
#pragma unroll
  for (int x = 0; x < 4; ++x) arow[x] = (wm + x * 32 + l31) * 64;
#pragma unroll
  for (int y = 0; y < 2; ++y) brow[y] = (wn + y * 32 + l31) * 64;

  // register-pipelined fragment+MFMA pass over one staged K-tile
  auto do_tile = [&](const f16* sA, const f16* sB) {
    f16x8 af[2][4], bf[2][2];  // register double-buffer of fragments
    {
      const int pos = ((khalf) ^ rsw) * 8;
#pragma unroll
      for (int x = 0; x < 4; ++x)
        af[0][x] = *reinterpret_cast<const f16x8*>(&sA[arow[x] + pos]);
#pragma unroll
      for (int y = 0; y < 2; ++y)
        bf[0][y] = *reinterpret_cast<const f16x8*>(&sB[brow[y] + pos]);
    }
#pragma unroll
    for (int c = 0; c < 4; ++c) {  // c compile-time: af[c&1] stays in regs
      const int cb = c & 1, nb = cb ^ 1;
      if (c < 3) {  // issue chunk c+1 reads BEFORE chunk c's MFMAs
        const int pos = (((c + 1) * 2 + khalf) ^ rsw) * 8;
#pragma unroll
        for (int x = 0; x < 4; ++x)
          af[nb][x] = *reinterpret_cast<const f16x8*>(&sA[arow[x] + pos]);
#pragma unroll
        for (int y = 0; y < 2; ++y)
          bf[nb][y] = *reinterpret_cast<const f16x8*>(&sB[brow[y] + pos]);
      }
      __builtin_amdgcn_s_setprio(1);
#pragma unroll
      for (int x = 0; x < 4; ++x)
#pragma unroll
        for (int y = 0; y < 2; ++y)
          acc[x][y] = __builtin_amdgcn_mfma_f32_32x32x16_f16(af[cb][x], bf[cb][y], acc[x][y], 0, 0, 0);
      __builtin_amdgcn_s_setprio(0);
    }
  };

  if constexpr (DBUF) {
    // ---- prologue: stage K-tile 0 into buffer 0
    {
      f16* pA = (f16*)smem;
      f16* pB = (f16*)(smem + 32768);
#pragma unroll
      for (int j = 0; j < 4; ++j) GLD16(gA + aoff[j], &pA[loff[j]]);
#pragma unroll
      for (int j = 0; j < 4; ++j) GLD16(gB + boff[j], &pB[loff[j]]);
    }
    asm volatile("s_waitcnt vmcnt(0)" ::: "memory");
    __builtin_amdgcn_s_barrier();

    for (int t = 0; t < nt; ++t) {
      const int cur = t & 1;
      const f16* sA = (const f16*)(smem + cur * 65536);
      const f16* sB = (const f16*)(smem + cur * 65536 + 32768);
      const bool pf = (t + 1 < nt);
      if (pf) {  // issue t+1's staging (retired at tile end)
        f16* pA = (f16*)(smem + (cur ^ 1) * 65536);
        f16* pB = (f16*)(smem + (cur ^ 1) * 65536 + 32768);
        const int kg = (t + 1) * 64;
#pragma unroll
        for (int j = 0; j < 4; ++j) GLD16(gA + aoff[j] + kg, &pA[loff[j]]);
#pragma unroll
        for (int j = 0; j < 4; ++j) GLD16(gB + boff[j] + kg, &pB[loff[j]]);
      }
      do_tile(sA, sB);
      if (pf) asm volatile("s_waitcnt vmcnt(0)" ::: "memory");
      __builtin_amdgcn_s_barrier();
    }
  } else {
    f16* sA = (f16*)smem;
    f16* sB = (f16*)(smem + 32768);
    for (int t = 0; t < nt; ++t) {
      const int kg = t * 64;
#pragma unroll
      for (int j = 0; j < 4; ++j) GLD16(gA + aoff[j] + kg, &sA[loff[j]]);
#pragma unroll
      for (int j = 0; j < 4; ++j) GLD16(gB + boff[j] + kg, &sB[loff[j]]);
      asm volatile("s_waitcnt vmcnt(0)" ::: "memory");
      __builtin_amdgcn_s_barrier();
      do_tile(sA, sB);
      __builtin_amdgcn_s_barrier();  // protect buffer before next stage
    }
  }

  // ---- V epilogue (MODE 0, seg==2): LDS transpose, four 64-col passes
  if (MODE == 0 && (tileN >> 11) == 2) {
    const int nn0 = tileN - 2 * H;
    const int b = tileM >> 12, s0 = tileM & (S - 1);
    f16* sT = (f16*)smem;  // [col 0..63][row 0..255], stride 264 (33792 B)
#pragma unroll
    for (int p = 0; p < 4; ++p) {
      if ((wave & 3) == p) {
#pragma unroll
        for (int x = 0; x < 4; ++x)
#pragma unroll
          for (int y = 0; y < 2; ++y) {
            int scol = y * 32 + l31;
            float bias = x2[nn0 + p * 64 + scol];
#pragma unroll
            for (int g = 0; g < 4; ++g) {
              int row = wm + x * 32 + g * 8 + khalf * 4;
              f16x4 h4 = {(f16)(acc[x][y][g * 4 + 0] + bias),
                          (f16)(acc[x][y][g * 4 + 1] + bias),
                          (f16)(acc[x][y][g * 4 + 2] + bias),
                          (f16)(acc[x][y][g * 4 + 3] + bias)};
              *reinterpret_cast<f16x4*>(&sT[scol * 264 + row]) = h4;
            }
          }
      }
      __syncthreads();
      {
        int c = tid >> 3, hh = tid & 7;
        const f16* src = &sT[c * 264 + hh * 32];
        f16* dst = (f16*)C2 + (size_t)b * H * S + (size_t)(nn0 + p * 64 + c) * S +
                   s0 + hh * 32;
#pragma unroll
        for (int j = 0; j < 4; ++j)
          reinterpret_cast<f16x8*>(dst)[j] = reinterpret_cast<const f16x8*>(src)[j];
      }
      __syncthreads();
    }
    return;
  }

#pragma unroll
  for (int x = 0; x < 4; ++x)
#pragma unroll
    for (int y = 0; y < 2; ++y)
#pragma unroll
      for (int r = 0; r < 16; ++r) {
        int m = tileM + wm + x * 32 + (r & 3) + 8 * (r >> 2) + 4 * khalf;
        int n = tileN + wn + y * 32 + l31;
        float v = acc[x][y][r];
        if (MODE == 0) {
          int seg = n >> 11, nn = n & 2047;  // seg 0/1 only (V handled above)
          if (seg == 0) {
            ((f16*)C0)[(size_t)m * H + nn] = (f16)(v + x0[nn]);
          } else {
            ((f16*)C1)[(size_t)m * H + nn] = (f16)(v + x1[nn]);
          }
        } else if (MODE == 2) {
          int b = m >> 12;
          ((f16*)C0)[(size_t)m * S + n] = (f16)(v * scale + x0[(size_t)b * S + n]);
        } else {
          ((float*)C0)[(size_t)m * H + n] = v;
        }
      }
}

// ------------------------------------------------- softmax over 4096 f16, in place
__global__ __launch_bounds__(256) void softmax_f16(f16* __restrict__ sc) {
  const int tid = threadIdx.x;
  f16* rp = sc + (size_t)blockIdx.x * S;
  f16x8 h[2];
#pragma unroll
  for (int j = 0; j < 2; ++j) h[j] = reinterpret_cast<f16x8*>(rp)[tid + j * 256];

  float v[16];
#pragma unroll
  for (int j = 0; j < 2; ++j)
#pragma unroll
    for (int e = 0; e < 8; ++e) v[j * 8 + e] = (float)h[j][e];

  float m = -1e30f;
#pragma unroll
  for (int e = 0; e < 16; ++e) m = fmaxf(m, v[e]);
#pragma unroll
  for (int off = 32; off; off >>= 1) m = fmaxf(m, __shfl_xor(m, off));

  __shared__ float red[8];
  int wave = tid >> 6, lane = tid & 63;
  if (lane == 0) red[wave] = m;
  __syncthreads();
  m = fmaxf(fmaxf(red[0], red[1]), fmaxf(red[2], red[3]));

  float s = 0.f;
#pragma unroll
  for (int e = 0; e < 16; ++e) { v[e] = __expf(v[e] - m); s += v[e]; }
#pragma unroll
  for (int off = 32; off; off >>= 1) s += __shfl_xor(s, off);
  if (lane == 0) red[4 + wave] = s;
  __syncthreads();
  s = red[4] + red[5] + red[6] + red[7];
  float inv = 1.0f / s;

#pragma unroll
  for (int j = 0; j < 2; ++j) {
#pragma unroll
    for (int e = 0; e < 8; ++e) h[j][e] = (f16)(v[j * 8 + e] * inv);
    reinterpret_cast<f16x8*>(rp)[tid + j * 256] = h[j];
  }
}

// ---------------------------------------------------------------- launch
extern "C" void kernel_launch(void* const* d_in, const int* in_sizes, int n_in,
                              void* d_out, int out_size, void* d_ws, size_t ws_size,
                              hipStream_t stream) {
  const float* hs   = (const float*)d_in[0];
  const float* mask = (const float*)d_in[1];
  const float* Wq   = (const float*)d_in[2];
  const float* bq   = (const float*)d_in[3];
  const float* Wk   = (const float*)d_in[4];
  const float* bk   = (const float*)d_in[5];
  const float* Wv   = (const float*)d_in[6];
  const float* bv   = (const float*)d_in[7];
  float* out = (float*)d_out;

  // workspace layout (~226 MB)
  f16* hs_h = (f16*)d_ws;                        // B*S*H
  f16* w_h  = hs_h + (size_t)B * S * H;          // 3*H*H concat
  f16* Qh   = w_h + (size_t)3 * H * H;           // B*S*H
  f16* Kh   = Qh + (size_t)B * S * H;            // B*S*H
  f16* Vt   = Kh + (size_t)B * S * H;            // B*H*S (transposed)
  f16* Sc   = Vt + (size_t)B * S * H;            // B*S*S f16

  const int castN = B * S * H / 4 + 3 * H * H / 4;
  cast_all<<<(castN + 255) / 256, 256, 0, stream>>>(hs, Wq, Wk, Wv, hs_h, w_h);

  dim3 blk(512);
  const float sscale = 0.088388347648318447f;  // 1/sqrt(HEAD_SIZE=128)

  // fused QKV: M=8192, N=6144, K=2048. grid (24,32): 768 blocks, 2-3/CU
  gemm_tn<0, false><<<dim3(24, 32), blk, 0, stream>>>(
      hs_h, w_h, Qh, Kh, Vt, bq, bk, bv, 1.f, H, H, H);

  // scores both batches: M=8192, N=4096, K=2048. grid (16,32): 512 = 2/CU
  gemm_tn<2, false><<<dim3(16, 32), blk, 0, stream>>>(
      Qh, Kh, Sc, nullptr, nullptr, mask, nullptr, nullptr, sscale, H, H, H);

  softmax_f16<<<B * S, 256, 0, stream>>>(Sc);

  // PV both batches: M=8192, N=2048, K=4096. grid (8,32): 256 = 1/CU -> DBUF
  gemm_tn<3, true><<<dim3(8, 32), blk, 0, stream>>>(
      Sc, Vt, out, nullptr, nullptr, nullptr, nullptr, nullptr, 1.f, S, S, S);
}

// Round 6
// 630.471 us; speedup vs baseline: 1.1181x; 1.1181x over previous
//
#include <hip/hip_runtime.h>

typedef _Float16 f16;
typedef _Float16 f16x8 __attribute__((ext_vector_type(8)));
typedef _Float16 f16x4 __attribute__((ext_vector_type(4)));
typedef float    f32x4 __attribute__((ext_vector_type(4)));

#define GLD16(g, l)                                                            \
  __builtin_amdgcn_global_load_lds(                                            \
      (const __attribute__((address_space(1))) void*)(g),                      \
      (__attribute__((address_space(3))) void*)(l), 16, 0, 0)

static constexpr int S = 4096, H = 2048, B = 2;

// ------------------------------------------- single fused cast: hs | Wq|Wk|Wv
__global__ __launch_bounds__(256) void cast_all(
    const float* __restrict__ hs, const float* __restrict__ w0,
    const float* __restrict__ w1, const float* __restrict__ w2,
    f16* __restrict__ hs_h, f16* __restrict__ w_h) {
  const int hsN4 = B * S * H / 4;  // float4 groups in hs
  const int wN4  = H * H / 4;     // float4 groups per weight
  int i = blockIdx.x * 256 + threadIdx.x;
  float4 f;
  if (i < hsN4) {
    f = reinterpret_cast<const float4*>(hs)[i];
    f16x4 h = {(f16)f.x, (f16)f.y, (f16)f.z, (f16)f.w};
    reinterpret_cast<f16x4*>(hs_h)[i] = h;
  } else {
    int j = i - hsN4;
    int seg = j / wN4, off = j - seg * wN4;
    const float* src = seg == 0 ? w0 : (seg == 1 ? w1 : w2);
    f = reinterpret_cast<const float4*>(src)[off];
    f16x4 h = {(f16)f.x, (f16)f.y, (f16)f.z, (f16)f.w};
    reinterpret_cast<f16x4*>(w_h)[j] = h;
  }
}

// ---------------------------------------------------------------- TN GEMM
// C[m,n] = sum_k A[m,k]*B[n,k].
// BM=BN=256, BK=64, 512 threads = 8 waves (2M x 4N), per-wave 128x64 output
// as 8x4 fragments of 16x16x32 MFMA (acc[8][4] f32x4 = 128 regs).
// m201-faithful 4-phase schedule per K-tile (two barriers per phase):
//   phase 0: read ALL B-frags (8 b128, register-carried for the whole tile)
//            + A-slab0 (4 b128); issue 8 GLD prefetch of tile t+1;
//            barrier; lgkmcnt(0); sched_barrier; setprio(1); 16 MFMA;
//            setprio(0); barrier.
//   phase 1..3: read A-slab p (4 b128); same barrier/MFMA pattern.
//   vmcnt(0) before the last trailing barrier retires t+1's staging
//   (issued 4 phases earlier, ~2000cy cover).
// LDS: double buffer, 2 x (A[256][64] + B[256][64]) f16 = 128KB.
// LDS swizzle (proven, and bank-even for the 16-lane fragment pattern):
// chunk (row,kc) stored at line-slot kc ^ (row&7) ^ ((row&16)>>2).
// 16x16x32 layouts: A/B-frag: lane&15 = row(col), k = (lane>>4)*8+e (8 f16
// contiguous). C/D: col = lane&15, row = (lane>>4)*4 + r (HW-verified).
// MODE 0: fused QKV.  n<2048 -> Q(+bq) f16; <4096 -> K(+bk); else Vt[b][h][s](+bv)
// MODE 2: scores, batched. f16 out = v*scale + mask[b][n]
// MODE 3: PV, batched. f32 out.
template <int MODE>
__global__ __launch_bounds__(512, 2) void gemm_tn(
    const f16* __restrict__ A, const f16* __restrict__ Bm,
    void* __restrict__ C0, void* __restrict__ C1, void* __restrict__ C2,
    const float* __restrict__ x0, const float* __restrict__ x1,
    const float* __restrict__ x2, float scale, int K, int lda, int ldb) {
  __shared__ __attribute__((aligned(16))) char smem[131072];

  const int tileM = blockIdx.y * 256;
  const int tileN = blockIdx.x * 256;

  const int tid  = threadIdx.x;
  const int wave = tid >> 6, lane = tid & 63;
  const int wm = (wave >> 2) * 128;  // 0,128
  const int wn = (wave & 3) * 64;    // 0,64,128,192
  const int ln = lane & 15, kq = lane >> 4;

  f32x4 acc[8][4] = {};

  // batch-aware operand row bases (tiles never straddle batches: S%256==0)
  size_t rowB = tileN;
  if (MODE == 2) rowB = (size_t)(tileM >> 12) * S + tileN;  // Kh row = b*S + k
  if (MODE == 3) rowB = (size_t)(tileM >> 12) * H + tileN;  // Vt row = b*H + h
  const f16* gA = A + (size_t)tileM * lda;
  const f16* gB = Bm + rowB * ldb;

  // staging offsets: 256 rows x 8 chunks(16B) per operand = 4 gloads each
  int aoff[4], boff[4], loff[4];
#pragma unroll
  for (int j = 0; j < 4; ++j) {
    int id = j * 512 + tid;
    int r = id >> 3, cs = (id & 7) ^ (r & 7) ^ ((r & 16) >> 2);
    aoff[j] = r * lda + cs * 8;
    boff[j] = r * ldb + cs * 8;
    loff[j] = id * 8;
  }

  const int nt = K >> 6;

  // fragment read: row-major [256][64] f16 tile, logical chunk cc = ks*4+kq,
  // stored at slot cc ^ (row&7) ^ ((row&16)>>2)
  auto rdfrag = [&](const f16* sT, int rbase, int ks) -> f16x8 {
    const int row = rbase + ln;
    const int slot = (ks * 4 + kq) ^ (row & 7) ^ ((row & 16) >> 2);
    return *reinterpret_cast<const f16x8*>(&sT[row * 64 + slot * 8]);
  };

  // ---- prologue: stage K-tile 0 into buffer 0
  {
    f16* pA = (f16*)smem;
    f16* pB = (f16*)(smem + 32768);
#pragma unroll
    for (int j = 0; j < 4; ++j) GLD16(gA + aoff[j], &pA[loff[j]]);
#pragma unroll
    for (int j = 0; j < 4; ++j) GLD16(gB + boff[j], &pB[loff[j]]);
  }
  asm volatile("s_waitcnt vmcnt(0)" ::: "memory");
  __builtin_amdgcn_s_barrier();

  for (int t = 0; t < nt; ++t) {
    const int cur = t & 1;
    const f16* sA = (const f16*)(smem + cur * 65536);
    const f16* sB = (const f16*)(smem + cur * 65536 + 32768);
    f16* pA = (f16*)(smem + (cur ^ 1) * 65536);
    f16* pB = (f16*)(smem + (cur ^ 1) * 65536 + 32768);
    const int kg = (t + 1) * 64;
    const bool pf = (t + 1 < nt);

    f16x8 bf[2][4];  // [ks][y] register-carried across the whole K-tile

    // ======== phase 0: B-all + A-slab0 reads | staging issue ========
#pragma unroll
    for (int ks = 0; ks < 2; ++ks)
#pragma unroll
      for (int y = 0; y < 4; ++y) bf[ks][y] = rdfrag(sB, wn + y * 16, ks);
    f16x8 a00 = rdfrag(sA, wm + 0 * 16, 0), a01 = rdfrag(sA, wm + 0 * 16, 1);
    f16x8 a10 = rdfrag(sA, wm + 1 * 16, 0), a11 = rdfrag(sA, wm + 1 * 16, 1);
    if (pf) {
#pragma unroll
      for (int j = 0; j < 4; ++j) GLD16(gA + aoff[j] + kg, &pA[loff[j]]);
#pragma unroll
      for (int j = 0; j < 4; ++j) GLD16(gB + boff[j] + kg, &pB[loff[j]]);
    }
    __builtin_amdgcn_s_barrier();
    asm volatile("s_waitcnt lgkmcnt(0)" ::: "memory");
    __builtin_amdgcn_sched_barrier(0);
    __builtin_amdgcn_s_setprio(1);
#pragma unroll
    for (int y = 0; y < 4; ++y) {
      acc[0][y] = __builtin_amdgcn_mfma_f32_16x16x32_f16(a00, bf[0][y], acc[0][y], 0, 0, 0);
      acc[1][y] = __builtin_amdgcn_mfma_f32_16x16x32_f16(a10, bf[0][y], acc[1][y], 0, 0, 0);
    }
#pragma unroll
    for (int y = 0; y < 4; ++y) {
      acc[0][y] = __builtin_amdgcn_mfma_f32_16x16x32_f16(a01, bf[1][y], acc[0][y], 0, 0, 0);
      acc[1][y] = __builtin_amdgcn_mfma_f32_16x16x32_f16(a11, bf[1][y], acc[1][y], 0, 0, 0);
    }
    __builtin_amdgcn_s_setprio(0);
    __builtin_amdgcn_s_barrier();

    // ======== phases 1..3: A-slab p ========
#pragma unroll
    for (int p = 1; p < 4; ++p) {
      f16x8 b00 = rdfrag(sA, wm + (2 * p + 0) * 16, 0);
      f16x8 b01 = rdfrag(sA, wm + (2 * p + 0) * 16, 1);
      f16x8 b10 = rdfrag(sA, wm + (2 * p + 1) * 16, 0);
      f16x8 b11 = rdfrag(sA, wm + (2 * p + 1) * 16, 1);
      __builtin_amdgcn_s_barrier();
      asm volatile("s_waitcnt lgkmcnt(0)" ::: "memory");
      __builtin_amdgcn_sched_barrier(0);
      __builtin_amdgcn_s_setprio(1);
#pragma unroll
      for (int y = 0; y < 4; ++y) {
        acc[2 * p + 0][y] = __builtin_amdgcn_mfma_f32_16x16x32_f16(b00, bf[0][y], acc[2 * p + 0][y], 0, 0, 0);
        acc[2 * p + 1][y] = __builtin_amdgcn_mfma_f32_16x16x32_f16(b10, bf[0][y], acc[2 * p + 1][y], 0, 0, 0);
      }
#pragma unroll
      for (int y = 0; y < 4; ++y) {
        acc[2 * p + 0][y] = __builtin_amdgcn_mfma_f32_16x16x32_f16(b01, bf[1][y], acc[2 * p + 0][y], 0, 0, 0);
        acc[2 * p + 1][y] = __builtin_amdgcn_mfma_f32_16x16x32_f16(b11, bf[1][y], acc[2 * p + 1][y], 0, 0, 0);
      }
      __builtin_amdgcn_s_setprio(0);
      if (p == 3 && pf)  // retire t+1's staging (issued 4 phases ago)
        asm volatile("s_waitcnt vmcnt(0)" ::: "memory");
      __builtin_amdgcn_s_barrier();
    }
  }

  // ---- V epilogue (MODE 0, seg==2): LDS transpose, four 64-col passes
  if (MODE == 0 && (tileN >> 11) == 2) {
    const int nn0 = tileN - 2 * H;
    const int b = tileM >> 12, s0 = tileM & (S - 1);
    f16* sT = (f16*)smem;  // [col 0..63][row 0..255], stride 264 (33792 B)
#pragma unroll
    for (int p = 0; p < 4; ++p) {
      if ((wave & 3) == p) {
#pragma unroll
        for (int x = 0; x < 8; ++x)
#pragma unroll
          for (int y = 0; y < 4; ++y) {
            int scol = y * 16 + ln;
            float bias = x2[nn0 + p * 64 + scol];
            int row0 = wm + x * 16 + kq * 4;
            f16x4 h4 = {(f16)(acc[x][y][0] + bias), (f16)(acc[x][y][1] + bias),
                        (f16)(acc[x][y][2] + bias), (f16)(acc[x][y][3] + bias)};
            *reinterpret_cast<f16x4*>(&sT[scol * 264 + row0]) = h4;
          }
      }
      __syncthreads();
      {
        int c = tid >> 3, hh = tid & 7;
        const f16* src = &sT[c * 264 + hh * 32];
        f16* dst = (f16*)C2 + (size_t)b * H * S + (size_t)(nn0 + p * 64 + c) * S +
                   s0 + hh * 32;
#pragma unroll
        for (int j = 0; j < 4; ++j)
          reinterpret_cast<f16x8*>(dst)[j] = reinterpret_cast<const f16x8*>(src)[j];
      }
      __syncthreads();
    }
    return;
  }

#pragma unroll
  for (int x = 0; x < 8; ++x)
#pragma unroll
    for (int y = 0; y < 4; ++y)
#pragma unroll
      for (int r = 0; r < 4; ++r) {
        int m = tileM + wm + x * 16 + kq * 4 + r;
        int n = tileN + wn + y * 16 + ln;
        float v = acc[x][y][r];
        if (MODE == 0) {
          int seg = n >> 11, nn = n & 2047;  // seg 0/1 only (V handled above)
          if (seg == 0) {
            ((f16*)C0)[(size_t)m * H + nn] = (f16)(v + x0[nn]);
          } else {
            ((f16*)C1)[(size_t)m * H + nn] = (f16)(v + x1[nn]);
          }
        } else if (MODE == 2) {
          int b = m >> 12;
          ((f16*)C0)[(size_t)m * S + n] = (f16)(v * scale + x0[(size_t)b * S + n]);
        } else {
          ((float*)C0)[(size_t)m * H + n] = v;
        }
      }
}

// ------------------------------------------------- softmax over 4096 f16, in place
__global__ __launch_bounds__(256) void softmax_f16(f16* __restrict__ sc) {
  const int tid = threadIdx.x;
  f16* rp = sc + (size_t)blockIdx.x * S;
  f16x8 h[2];
#pragma unroll
  for (int j = 0; j < 2; ++j) h[j] = reinterpret_cast<f16x8*>(rp)[tid + j * 256];

  float v[16];
#pragma unroll
  for (int j = 0; j < 2; ++j)
#pragma unroll
    for (int e = 0; e < 8; ++e) v[j * 8 + e] = (float)h[j][e];

  float m = -1e30f;
#pragma unroll
  for (int e = 0; e < 16; ++e) m = fmaxf(m, v[e]);
#pragma unroll
  for (int off = 32; off; off >>= 1) m = fmaxf(m, __shfl_xor(m, off));

  __shared__ float red[8];
  int wave = tid >> 6, lane = tid & 63;
  if (lane == 0) red[wave] = m;
  __syncthreads();
  m = fmaxf(fmaxf(red[0], red[1]), fmaxf(red[2], red[3]));

  float s = 0.f;
#pragma unroll
  for (int e = 0; e < 16; ++e) { v[e] = __expf(v[e] - m); s += v[e]; }
#pragma unroll
  for (int off = 32; off; off >>= 1) s += __shfl_xor(s, off);
  if (lane == 0) red[4 + wave] = s;
  __syncthreads();
  s = red[4] + red[5] + red[6] + red[7];
  float inv = 1.0f / s;

#pragma unroll
  for (int j = 0; j < 2; ++j) {
#pragma unroll
    for (int e = 0; e < 8; ++e) h[j][e] = (f16)(v[j * 8 + e] * inv);
    reinterpret_cast<f16x8*>(rp)[tid + j * 256] = h[j];
  }
}

// ---------------------------------------------------------------- launch
extern "C" void kernel_launch(void* const* d_in, const int* in_sizes, int n_in,
                              void* d_out, int out_size, void* d_ws, size_t ws_size,
                              hipStream_t stream) {
  const float* hs   = (const float*)d_in[0];
  const float* mask = (const float*)d_in[1];
  const float* Wq   = (const float*)d_in[2];
  const float* bq   = (const float*)d_in[3];
  const float* Wk   = (const float*)d_in[4];
  const float* bk   = (const float*)d_in[5];
  const float* Wv   = (const float*)d_in[6];
  const float* bv   = (const float*)d_in[7];
  float* out = (float*)d_out;

  // workspace layout (~226 MB)
  f16* hs_h = (f16*)d_ws;                        // B*S*H
  f16* w_h  = hs_h + (size_t)B * S * H;          // 3*H*H concat
  f16* Qh   = w_h + (size_t)3 * H * H;           // B*S*H
  f16* Kh   = Qh + (size_t)B * S * H;            // B*S*H
  f16* Vt   = Kh + (size_t)B * S * H;            // B*H*S (transposed)
  f16* Sc   = Vt + (size_t)B * S * H;            // B*S*S f16

  const int castN = B * S * H / 4 + 3 * H * H / 4;
  cast_all<<<(castN + 255) / 256, 256, 0, stream>>>(hs, Wq, Wk, Wv, hs_h, w_h);

  dim3 blk(512);
  const float sscale = 0.088388347648318447f;  // 1/sqrt(HEAD_SIZE=128)

  // fused QKV: M=8192, N=6144, K=2048. grid (24,32), x fastest
  gemm_tn<0><<<dim3(24, 32), blk, 0, stream>>>(
      hs_h, w_h, Qh, Kh, Vt, bq, bk, bv, 1.f, H, H, H);

  // scores both batches: M=8192, N=4096, K=2048. grid (16,32)
  gemm_tn<2><<<dim3(16, 32), blk, 0, stream>>>(
      Qh, Kh, Sc, nullptr, nullptr, mask, nullptr, nullptr, sscale, H, H, H);

  softmax_f16<<<B * S, 256, 0, stream>>>(Sc);

  // PV both batches: M=8192, N=2048, K=4096. grid (8,32)
  gemm_tn<3><<<dim3(8, 32), blk, 0, stream>>>(
      Sc, Vt, out, nullptr, nullptr, nullptr, nullptr, nullptr, 1.f, S, S, S);
}